// Round 13
// baseline (318.878 us; speedup 1.0000x reference)
//
#include <hip/hip_runtime.h>
#include <hip/hip_bf16.h>
#include <cstdint>
#include <cstddef>

#define BB 8
#define PP 3136
#define EPSV 1e-5f
#define SCQK 0.17677669529663687f

using bf16x8 = __attribute__((ext_vector_type(8))) short;
using f32x4  = __attribute__((ext_vector_type(4))) float;

__device__ __forceinline__ float bf2f(unsigned short u) {
    union { float f; unsigned int i; } c; c.i = ((unsigned int)u) << 16; return c.f;
}
__device__ __forceinline__ unsigned short f2bf(float f) {
    __hip_bfloat16 h = __float2bfloat16(f);
    union { __hip_bfloat16 h; unsigned short u; } c; c.h = h; return c.u;
}
__device__ __forceinline__ float gelu_f(float t) {
    return 0.5f * t * (1.0f + erff(t * 0.70710678118654752440f));
}
__device__ __forceinline__ float gelu_fast(float x) {
    float z = 1.5957691216057308f * (x + 0.044715f * x * x * x);
    return x / (1.0f + __expf(-z));
}
__device__ __forceinline__ void async16(const void* g, void* s) {
    __builtin_amdgcn_global_load_lds(
        (const __attribute__((address_space(1))) unsigned int*)g,
        (__attribute__((address_space(3))) unsigned int*)s, 16, 0, 0);
}
__device__ __forceinline__ uint4 pack8(const float* v) {
    uint4 o;
    o.x = (unsigned)f2bf(v[0]) | ((unsigned)f2bf(v[1]) << 16);
    o.y = (unsigned)f2bf(v[2]) | ((unsigned)f2bf(v[3]) << 16);
    o.z = (unsigned)f2bf(v[4]) | ((unsigned)f2bf(v[5]) << 16);
    o.w = (unsigned)f2bf(v[6]) | ((unsigned)f2bf(v[7]) << 16);
    return o;
}

// ---------- all weights f32 -> bf16, one launch ----------
__global__ __launch_bounds__(256) void cvt_all_k(
    const float* __restrict__ Wq, const float* __restrict__ Wm,
    const float* __restrict__ W1, const float* __restrict__ W2,
    unsigned short* __restrict__ dq, unsigned short* __restrict__ dm,
    unsigned short* __restrict__ d1, unsigned short* __restrict__ d2)
{
    int i = blockIdx.x * 256 + threadIdx.x;   // total 786432
    if (i < 196608) dq[i] = f2bf(Wq[i]);
    else if (i < 262144) dm[i - 196608] = f2bf(Wm[i - 196608]);
    else if (i < 524288) d1[i - 262144] = f2bf(W1[i - 262144]);
    else d2[i - 524288] = f2bf(W2[i - 524288]);
}

// ---------- transpose-in ----------
__global__ __launch_bounds__(256) void transin_k(const float* __restrict__ x,
    const float* __restrict__ g1, const float* __restrict__ b1,
    const float* __restrict__ m1, const float* __restrict__ v1,
    float* __restrict__ x_pm, unsigned short* __restrict__ h_bf)
{
    __shared__ float tile[64][65];
    __shared__ float gam[64], bet[64], mu[64], rst[64];
    const int p0 = blockIdx.x * 64, c0 = blockIdx.y * 64, b = blockIdx.z;
    const int t = threadIdx.x;
    if (t < 64) { int c = c0 + t; gam[t] = g1[c]; bet[t] = b1[c]; mu[t] = m1[c]; rst[t] = rsqrtf(v1[c] + EPSV); }
    {
        int cl = t >> 2, px = (t & 3) * 16;
        const float* src = x + ((size_t)(b * 256 + c0 + cl)) * PP + p0 + px;
        #pragma unroll
        for (int i4 = 0; i4 < 4; i4++) {
            float4 r0 = *(const float4*)(src + i4 * 4);
            tile[cl][px + i4*4 + 0] = r0.x; tile[cl][px + i4*4 + 1] = r0.y;
            tile[cl][px + i4*4 + 2] = r0.z; tile[cl][px + i4*4 + 3] = r0.w;
        }
    }
    __syncthreads();
    {
        int pl = t >> 2, cb = (t & 3) * 16;
        float raw[16], hg[16];
        #pragma unroll
        for (int i = 0; i < 16; i++) {
            float vv = tile[cb + i][pl];
            raw[i] = vv;
            hg[i] = gelu_fast(gam[cb + i] * (vv - mu[cb + i]) * rst[cb + i] + bet[cb + i]);
        }
        size_t off = ((size_t)b * PP + p0 + pl) * 256 + c0 + cb;
        float* xd = x_pm + off;
        #pragma unroll
        for (int i4 = 0; i4 < 4; i4++) {
            float4 o; o.x = raw[i4*4]; o.y = raw[i4*4+1]; o.z = raw[i4*4+2]; o.w = raw[i4*4+3];
            *(float4*)(xd + i4 * 4) = o;
        }
        uint4* hd = (uint4*)(h_bf + off);
        hd[0] = pack8(&hg[0]);
        hd[1] = pack8(&hg[8]);
    }
}

// ---------- MFMA GEMM, BM x 128 tile (BM = 128: 512thr 2x4 waves; BM = 64: 256thr 1x4) ----------
// BK=32, global_load_lds(16B), 2-buf dbuf, XOR-swizzled LDS both-sides,
// LDS-transpose epilogue. EPI 0/1/2/3 as before (EPI3 = fused NCHW transout).
template<int EPI, int BM>
__global__ __launch_bounds__(BM * 4) void gemm_mfma_k(
    const unsigned short* __restrict__ Aact,
    const unsigned short* __restrict__ Wbf,
    const int K, const int Mout,
    void* __restrict__ C1, void* __restrict__ C2,
    const float* __restrict__ e0, const float* __restrict__ e1,
    const float* __restrict__ e2, const float* __restrict__ e3,
    const float* __restrict__ resid)
{
    constexpr int ASTRIDE = BM * 32;                       // elems per A stage
    constexpr int SMEMSZ = (BM == 128) ? 32768 : 24576;
    __shared__ __align__(16) char smem[SMEMSZ];
    unsigned short* As0 = (unsigned short*)smem;
    unsigned short* Bs0 = (unsigned short*)(smem + 2 * ASTRIDE * 2);
    float* T = (float*)smem;

    const int tid = threadIdx.x;
    const int w = tid >> 6, lane = tid & 63, g = lane >> 4, l15 = lane & 15;
    const int wm = (BM == 128) ? (w >> 2) : 0;
    const int wn = w & 3;
    const size_t row0 = (size_t)blockIdx.x * BM;
    const int n0 = blockIdx.y * 128;
    const int srow = tid >> 2, scb = tid & 3;

    const f32x4 vzero = {0.f, 0.f, 0.f, 0.f};
    f32x4 acc[4][2];
    #pragma unroll
    for (int mf = 0; mf < 4; mf++)
        #pragma unroll
        for (int nf = 0; nf < 2; nf++) acc[mf][nf] = vzero;

    const int NT = K >> 5;
    const int cbp = scb ^ ((srow >> 1) & 3);
    const int dstoff = (tid & ~63) * 8;

    auto STAGE = [&](int s) {
        const int k0 = s << 5;
        async16(Aact + (row0 + srow) * K + k0 + cbp * 8, As0 + (s & 1) * ASTRIDE + dstoff);
        async16(Wbf + (size_t)(n0 + srow) * K + k0 + cbp * 8, Bs0 + (s & 1) * 4096 + dstoff);
        if (BM == 64) {  // second B unit: rows 64..127, same swizzle ((64+r)>>1 ≡ r>>1 mod 4)
            async16(Wbf + (size_t)(n0 + 64 + srow) * K + k0 + cbp * 8,
                    Bs0 + (s & 1) * 4096 + 2048 + dstoff);
        }
    };
    auto COMPUTE = [&](int t) {
        const unsigned short* Ab = As0 + (t & 1) * ASTRIDE;
        const unsigned short* Bb = Bs0 + (t & 1) * 4096;
        bf16x8 af[4], bfr[2];
        #pragma unroll
        for (int mf = 0; mf < 4; mf++) {
            int row = wm * 64 + mf * 16 + l15;
            int gb = g ^ ((row >> 1) & 3);
            af[mf] = *(const bf16x8*)&Ab[row * 32 + gb * 8];
        }
        #pragma unroll
        for (int nf = 0; nf < 2; nf++) {
            int row = wn * 32 + nf * 16 + l15;
            int gb = g ^ ((row >> 1) & 3);
            bfr[nf] = *(const bf16x8*)&Bb[row * 32 + gb * 8];
        }
        #pragma unroll
        for (int mf = 0; mf < 4; mf++)
            #pragma unroll
            for (int nf = 0; nf < 2; nf++)
                acc[mf][nf] = __builtin_amdgcn_mfma_f32_16x16x32_bf16(af[mf], bfr[nf], acc[mf][nf], 0, 0, 0);
    };

    STAGE(0);
    for (int t = 0; t < NT; ++t) {
        __syncthreads();
        if (t + 1 < NT) STAGE(t + 1);
        COMPUTE(t);
    }

    // ---- LDS-transpose epilogue over 32-row slabs, T[32][132] ----
    __syncthreads();
    constexpr int NPASS = BM / 32;
    constexpr int RW = (BM == 128) ? 8 : 16;               // floats per thread per pass
    const int erow = (BM == 128) ? (tid >> 4) : (tid >> 3);
    const int col0 = (BM == 128) ? ((tid & 15) * 8) : ((tid & 7) * 16);
    #pragma unroll
    for (int p = 0; p < NPASS; ++p) {
        if (p) __syncthreads();
        if (wm == (p >> 1)) {
            const int mfb = (p & 1) * 2;
            #pragma unroll
            for (int mo = 0; mo < 2; mo++)
                #pragma unroll
                for (int nf = 0; nf < 2; nf++)
                    #pragma unroll
                    for (int r = 0; r < 4; r++)
                        T[(mo * 16 + g * 4 + r) * 132 + wn * 32 + nf * 16 + l15] = acc[mfb + mo][nf][r];
        }
        __syncthreads();
        if (EPI == 3) {
            {   // bn + resid row-major (coalesced), in-place on T
                const size_t prow = row0 + p * 32 + erow;
                const size_t offr = prow * 256 + n0 + col0;
                #pragma unroll
                for (int i = 0; i < RW / 4; i++) {
                    float4 v  = *(const float4*)&T[erow * 132 + col0 + i * 4];
                    float4 ga = *(const float4*)(e0 + n0 + col0 + i * 4);
                    float4 be = *(const float4*)(e1 + n0 + col0 + i * 4);
                    float4 mm = *(const float4*)(e2 + n0 + col0 + i * 4);
                    float4 vv = *(const float4*)(e3 + n0 + col0 + i * 4);
                    float4 rr = *(const float4*)(resid + offr + i * 4);
                    float4 o;
                    o.x = ga.x * (v.x - mm.x) * rsqrtf(vv.x + EPSV) + be.x + rr.x;
                    o.y = ga.y * (v.y - mm.y) * rsqrtf(vv.y + EPSV) + be.y + rr.y;
                    o.z = ga.z * (v.z - mm.z) * rsqrtf(vv.z + EPSV) + be.z + rr.z;
                    o.w = ga.w * (v.w - mm.w) * rsqrtf(vv.w + EPSV) + be.w + rr.w;
                    *(float4*)&T[erow * 132 + col0 + i * 4] = o;
                }
            }
            __syncthreads();
            if (tid < 256) {   // NCHW store: thread = (m, 16-p slab)
                const int m = tid & 127, ph2 = tid >> 7;
                const int prow16 = (int)row0 + p * 32 + ph2 * 16;
                const int bimg = prow16 / PP;
                const int pp = prow16 - bimg * PP;
                float* dst = (float*)C1 + ((size_t)(bimg * 256 + n0 + m)) * PP + pp;
                #pragma unroll
                for (int i = 0; i < 4; i++) {
                    float4 o;
                    o.x = T[(ph2 * 16 + i * 4 + 0) * 132 + m];
                    o.y = T[(ph2 * 16 + i * 4 + 1) * 132 + m];
                    o.z = T[(ph2 * 16 + i * 4 + 2) * 132 + m];
                    o.w = T[(ph2 * 16 + i * 4 + 3) * 132 + m];
                    *(float4*)(dst + i * 4) = o;
                }
            }
        } else {
            float vals[RW];
            #pragma unroll
            for (int i = 0; i < RW / 4; i++) {
                float4 v = *(const float4*)&T[erow * 132 + col0 + i * 4];
                vals[i*4+0] = v.x; vals[i*4+1] = v.y; vals[i*4+2] = v.z; vals[i*4+3] = v.w;
            }
            const size_t prow = row0 + p * 32 + erow;
            const int mc0 = n0 + col0;
            const size_t off = prow * Mout + mc0;
            if (EPI == 0) {
                const float s = (mc0 < 256) ? SCQK : 1.0f;
                #pragma unroll
                for (int j = 0; j < RW; j++) vals[j] *= s;
                #pragma unroll
                for (int i = 0; i < RW / 8; i++)
                    *(uint4*)((unsigned short*)C1 + off + i * 8) = pack8(&vals[i * 8]);
            } else if (EPI == 1) {
                #pragma unroll
                for (int i = 0; i < RW / 4; i++) {
                    float4 bi = *(const float4*)(e0 + mc0 + i * 4);
                    float4 rr = *(const float4*)(resid + off + i * 4);
                    vals[i*4+0] += bi.x + rr.x; vals[i*4+1] += bi.y + rr.y;
                    vals[i*4+2] += bi.z + rr.z; vals[i*4+3] += bi.w + rr.w;
                }
                float4* d1 = (float4*)((float*)C1 + off);
                #pragma unroll
                for (int i = 0; i < RW / 4; i++) {
                    float4 o; o.x = vals[i*4]; o.y = vals[i*4+1]; o.z = vals[i*4+2]; o.w = vals[i*4+3];
                    d1[i] = o;
                }
                #pragma unroll
                for (int i = 0; i < RW / 8; i++)
                    *(uint4*)((unsigned short*)C2 + off + i * 8) = pack8(&vals[i * 8]);
            } else {  // EPI == 2
                #pragma unroll
                for (int i = 0; i < RW / 4; i++) {
                    float4 ga = *(const float4*)(e0 + mc0 + i * 4);
                    float4 be = *(const float4*)(e1 + mc0 + i * 4);
                    float4 mm = *(const float4*)(e2 + mc0 + i * 4);
                    float4 vv = *(const float4*)(e3 + mc0 + i * 4);
                    vals[i*4+0] = gelu_fast(ga.x * (vals[i*4+0] - mm.x) * rsqrtf(vv.x + EPSV) + be.x);
                    vals[i*4+1] = gelu_fast(ga.y * (vals[i*4+1] - mm.y) * rsqrtf(vv.y + EPSV) + be.y);
                    vals[i*4+2] = gelu_fast(ga.z * (vals[i*4+2] - mm.z) * rsqrtf(vv.z + EPSV) + be.z);
                    vals[i*4+3] = gelu_fast(ga.w * (vals[i*4+3] - mm.w) * rsqrtf(vv.w + EPSV) + be.w);
                }
                #pragma unroll
                for (int i = 0; i < RW / 8; i++)
                    *(uint4*)((unsigned short*)C1 + off + i * 8) = pack8(&vals[i * 8]);
            }
        }
    }
}

// ---------- exact-f32 window pooling of h ----------
__global__ __launch_bounds__(256) void poolh_k(const float* __restrict__ x_pm,
    const float* __restrict__ g1, const float* __restrict__ b1,
    const float* __restrict__ m1, const float* __restrict__ v1,
    float* __restrict__ ph)
{
    __shared__ float part[4][256];
    __shared__ float gam[256], bet[256], mu[256], rst[256];
    const int n = blockIdx.x, b = blockIdx.y, t = threadIdx.x;
    gam[t] = g1[t]; bet[t] = b1[t]; mu[t] = m1[t]; rst[t] = rsqrtf(v1[t] + EPSV);
    __syncthreads();
    const int c4 = (t & 63) * 4, pg = t >> 6;
    float s0 = 0.f, s1 = 0.f, s2 = 0.f, s3 = 0.f;
    for (int j = pg; j < 49; j += 4) {
        int p = ((n >> 3) * 7 + j / 7) * 56 + (n & 7) * 7 + j % 7;
        float4 vx = *(const float4*)(x_pm + ((size_t)b * PP + p) * 256 + c4);
        s0 += gelu_f(gam[c4+0] * (vx.x - mu[c4+0]) * rst[c4+0] + bet[c4+0]);
        s1 += gelu_f(gam[c4+1] * (vx.y - mu[c4+1]) * rst[c4+1] + bet[c4+1]);
        s2 += gelu_f(gam[c4+2] * (vx.z - mu[c4+2]) * rst[c4+2] + bet[c4+2]);
        s3 += gelu_f(gam[c4+3] * (vx.w - mu[c4+3]) * rst[c4+3] + bet[c4+3]);
    }
    part[pg][c4 + 0] = s0; part[pg][c4 + 1] = s1; part[pg][c4 + 2] = s2; part[pg][c4 + 3] = s3;
    __syncthreads();
    float tot = part[0][t] + part[1][t] + part[2][t] + part[3][t];
    ph[((size_t)b * 64 + n) * 256 + t] = tot * (1.0f / 49.0f);
}

// ---------- qr/kr ----------
__global__ __launch_bounds__(256) void qrkr_k(const float* __restrict__ ph,
    const float* __restrict__ Wqkv, float* __restrict__ qr, float* __restrict__ kr)
{
    __shared__ float row[256];
    const int n = blockIdx.x, b = blockIdx.y, t = threadIdx.x;
    row[t] = ph[((size_t)b * 64 + n) * 256 + t];
    __syncthreads();
    const float* wq = Wqkv + (size_t)t * 256;
    const float* wk = Wqkv + (size_t)(256 + t) * 256;
    float aq = 0.f, ak = 0.f;
    #pragma unroll 4
    for (int k = 0; k < 256; k += 4) {
        float4 a4 = *(const float4*)(wq + k);
        float4 b4 = *(const float4*)(wk + k);
        aq += row[k]*a4.x + row[k+1]*a4.y + row[k+2]*a4.z + row[k+3]*a4.w;
        ak += row[k]*b4.x + row[k+1]*b4.y + row[k+2]*b4.z + row[k+3]*b4.w;
    }
    qr[((size_t)b * 64 + n) * 256 + t] = aq;
    kr[((size_t)b * 64 + n) * 256 + t] = ak;
}

// ---------- aff row + top-8 ----------
__global__ __launch_bounds__(64) void topk_k(const float* __restrict__ qr,
    const float* __restrict__ kr, int* __restrict__ idxb)
{
    const int n = blockIdx.x, b_ = blockIdx.y;
    const int tid = threadIdx.x;
    __shared__ float qrow[256];
    *reinterpret_cast<float4*>(&qrow[tid * 4]) =
        *reinterpret_cast<const float4*>(qr + ((size_t)(b_ * 64) + n) * 256 + tid * 4);
    __syncthreads();
    const float* kp = kr + ((size_t)(b_ * 64) + tid) * 256;
    float av = 0.f;
    #pragma unroll 4
    for (int c = 0; c < 256; c++) av = fmaf(qrow[c], kp[c], av);
    for (int t = 0; t < 8; t++) {
        float v = av; int id = tid;
        #pragma unroll
        for (int off = 32; off; off >>= 1) {
            float v2 = __shfl_xor(v, off);
            int id2 = __shfl_xor(id, off);
            if (v2 > v || (v2 == v && id2 < id)) { v = v2; id = id2; }
        }
        if (tid == 0) idxb[((b_ * 64) + n) * 8 + t] = id;
        if (tid == id) av = -1e30f;
    }
}

// ---------- MFMA flash attention (round-11 proven): fixed-shift softmax + Pr LDS ----------
__global__ __launch_bounds__(256) void attn_mfma_k(const unsigned short* __restrict__ qkv,
    const int* __restrict__ idxb, unsigned short* __restrict__ msg)
{
    __shared__ __align__(16) unsigned short Ks[64 * 40];
    __shared__ __align__(16) unsigned short Vt[32 * 72];
    __shared__ __align__(16) unsigned short Pr[4][16 * 72];
    const int n = blockIdx.x, h = blockIdx.y, b = blockIdx.z;
    const int tid = threadIdx.x;
    const int w = tid >> 6, lane = tid & 63, g = lane >> 4, l15 = lane & 15;

    for (int e = tid; e < 64 * 40; e += 256) Ks[e] = 0;
    for (int e = tid; e < 32 * 72; e += 256) Vt[e] = 0;

    const int iq = w * 16 + l15;
    bf16x8 qf = {0, 0, 0, 0, 0, 0, 0, 0};
    if (iq < 49) {
        int p = ((n >> 3) * 7 + iq / 7) * 56 + (n & 7) * 7 + iq % 7;
        qf = *(const bf16x8*)(qkv + ((size_t)b * PP + p) * 768 + h * 32 + g * 8);
    }
    int widx[8];
    {
        const int* ip = idxb + ((b * 64) + n) * 8;
        #pragma unroll
        for (int t = 0; t < 8; t++) widx[t] = ip[t];
    }
    const f32x4 vzero = {0.f, 0.f, 0.f, 0.f};
    f32x4 o0 = vzero, o1 = vzero;
    float lsum = 0.f;

    const bool act = tid < 196;
    const int jrow = tid >> 2, c8 = (tid & 3) * 8;
    uint4 kk_r = {0,0,0,0}, vv_r = {0,0,0,0};
    auto LOADW = [&](int t) {
        int wsrc = widx[t];
        int p = ((wsrc >> 3) * 7 + jrow / 7) * 56 + (wsrc & 7) * 7 + jrow % 7;
        const unsigned short* srcp = qkv + ((size_t)b * PP + p) * 768 + 256 + h * 32 + c8;
        kk_r = *(const uint4*)srcp;
        vv_r = *(const uint4*)(srcp + 256);
    };
    if (act) LOADW(0);

    for (int t = 0; t < 8; t++) {
        __syncthreads();
        if (act) {
            *(uint4*)&Ks[jrow * 40 + c8] = kk_r;
            const unsigned short* pv = (const unsigned short*)&vv_r;
            #pragma unroll
            for (int jj = 0; jj < 8; jj++) {
                int dh = c8 + jj;
                Vt[dh * 72 + (jrow ^ (((dh >> 3) & 3) << 3))] = pv[jj];
            }
            if (t < 7) LOADW(t + 1);
        }
        __syncthreads();
        f32x4 s[4];
        #pragma unroll
        for (int nf = 0; nf < 4; nf++) {
            bf16x8 kf = *(const bf16x8*)&Ks[(nf * 16 + l15) * 40 + g * 8];
            s[nf] = __builtin_amdgcn_mfma_f32_16x16x32_bf16(kf, qf, vzero, 0, 0, 0);
        }
        float pe[16];
        #pragma unroll
        for (int nf = 0; nf < 4; nf++)
            #pragma unroll
            for (int r = 0; r < 4; r++) {
                int j = nf * 16 + g * 4 + r;
                float e_ = __expf(s[nf][r] - 10.0f);
                float pv_ = (j < 49) ? e_ : 0.f;
                pe[nf * 4 + r] = pv_;
                lsum += pv_;
            }
        #pragma unroll
        for (int nf = 0; nf < 4; nf++) {
            uint2 pw;
            pw.x = (unsigned)f2bf(pe[nf*4+0]) | ((unsigned)f2bf(pe[nf*4+1]) << 16);
            pw.y = (unsigned)f2bf(pe[nf*4+2]) | ((unsigned)f2bf(pe[nf*4+3]) << 16);
            *(uint2*)&Pr[w][l15 * 72 + nf * 16 + g * 4] = pw;
        }
        asm volatile("s_waitcnt lgkmcnt(0)" ::: "memory");
        __builtin_amdgcn_sched_barrier(0);
        #pragma unroll
        for (int ks = 0; ks < 2; ks++) {
            const int j0 = ks * 32 + g * 8;
            bf16x8 pf  = *(const bf16x8*)&Pr[w][l15 * 72 + j0];
            bf16x8 vf0 = *(const bf16x8*)&Vt[l15 * 72 + (j0 ^ (((l15 >> 3) & 1) << 3))];
            bf16x8 vf1 = *(const bf16x8*)&Vt[(16 + l15) * 72 + (j0 ^ ((2 + (l15 >> 3)) << 3))];
            o0 = __builtin_amdgcn_mfma_f32_16x16x32_bf16(vf0, pf, o0, 0, 0, 0);
            o1 = __builtin_amdgcn_mfma_f32_16x16x32_bf16(vf1, pf, o1, 0, 0, 0);
        }
    }
    lsum += __shfl_xor(lsum, 16);
    lsum += __shfl_xor(lsum, 32);
    if (iq < 49) {
        float inv = 1.0f / lsum;
        int p = ((n >> 3) * 7 + iq / 7) * 56 + (n & 7) * 7 + iq % 7;
        size_t off = ((size_t)b * PP + p) * 256 + h * 32;
        uint2 w0, w1;
        w0.x = (unsigned)f2bf(o0[0]*inv) | ((unsigned)f2bf(o0[1]*inv) << 16);
        w0.y = (unsigned)f2bf(o0[2]*inv) | ((unsigned)f2bf(o0[3]*inv) << 16);
        w1.x = (unsigned)f2bf(o1[0]*inv) | ((unsigned)f2bf(o1[1]*inv) << 16);
        w1.y = (unsigned)f2bf(o1[2]*inv) | ((unsigned)f2bf(o1[3]*inv) << 16);
        *(uint2*)(msg + off + g * 4) = w0;
        *(uint2*)(msg + off + 16 + g * 4) = w1;
    }
}

// ---------- depthwise 3x3 + bn3 + gelu ----------
__global__ __launch_bounds__(256) void dwconv_k(const unsigned short* __restrict__ in,
    const float* __restrict__ w9,
    const float* __restrict__ g3, const float* __restrict__ b3,
    const float* __restrict__ m3, const float* __restrict__ v3,
    unsigned short* __restrict__ out)
{
    __shared__ __align__(16) unsigned short tl[100 * 64];
    const int sx = blockIdx.x % 7, sy = blockIdx.x / 7;
    const int c0 = blockIdx.y * 64, b = blockIdx.z;
    const int t = threadIdx.x;
    for (int e = t; e < 800; e += 256) {
        int pos = e >> 3, c8 = (e & 7) * 8;
        int iy = sy * 8 + pos / 10 - 1, ix = sx * 8 + pos % 10 - 1;
        uint4 val = {0u, 0u, 0u, 0u};
        if (iy >= 0 && iy < 56 && ix >= 0 && ix < 56)
            val = *(const uint4*)(in + ((size_t)b * PP + iy * 56 + ix) * 1024 + c0 + c8);
        *(uint4*)&tl[pos * 64 + c8] = val;
    }
    __syncthreads();
    const int c2 = (t & 31) * 2, pg = t >> 5;
    const int c = c0 + c2;
    float w0[9], w1[9];
    #pragma unroll
    for (int i = 0; i < 9; i++) { w0[i] = w9[c * 9 + i]; w1[i] = w9[(c + 1) * 9 + i]; }
    const float ga0 = g3[c], be0 = b3[c], mu0 = m3[c], rs0 = rsqrtf(v3[c] + EPSV);
    const float ga1 = g3[c+1], be1 = b3[c+1], mu1 = m3[c+1], rs1 = rsqrtf(v3[c+1] + EPSV);
    #pragma unroll
    for (int q = 0; q < 8; q++) {
        int pos = pg * 8 + q, y = pos >> 3, xq = pos & 7;
        float s0 = 0.f, s1 = 0.f;
        #pragma unroll
        for (int dy = 0; dy < 3; dy++)
            #pragma unroll
            for (int dx = 0; dx < 3; dx++) {
                unsigned int u = *(const unsigned int*)&tl[((y + dy) * 10 + xq + dx) * 64 + c2];
                s0 = fmaf(bf2f((unsigned short)(u & 0xffffu)), w0[dy * 3 + dx], s0);
                s1 = fmaf(bf2f((unsigned short)(u >> 16)), w1[dy * 3 + dx], s1);
            }
        float y0 = gelu_fast(ga0 * (s0 - mu0) * rs0 + be0);
        float y1 = gelu_fast(ga1 * (s1 - mu1) * rs1 + be1);
        unsigned int ow = (unsigned int)f2bf(y0) | ((unsigned int)f2bf(y1) << 16);
        size_t off = ((size_t)b * PP + (sy * 8 + y) * 56 + sx * 8 + xq) * 1024 + c;
        *(unsigned int*)&out[off] = ow;
    }
}

// ---------- launch ----------
extern "C" void kernel_launch(void* const* d_in, const int* in_sizes, int n_in,
                              void* d_out, int out_size, void* d_ws, size_t ws_size,
                              hipStream_t stream)
{
    const float* x      = (const float*)d_in[0];
    const float* g1     = (const float*)d_in[1];
    const float* b1     = (const float*)d_in[2];
    const float* m1     = (const float*)d_in[3];
    const float* v1     = (const float*)d_in[4];
    const float* Wqkv   = (const float*)d_in[5];
    const float* Wmerge = (const float*)d_in[6];
    const float* bmerge = (const float*)d_in[7];
    const float* W1     = (const float*)d_in[8];
    const float* g2     = (const float*)d_in[9];
    const float* b2     = (const float*)d_in[10];
    const float* m2     = (const float*)d_in[11];
    const float* v2     = (const float*)d_in[12];
    const float* Wdw    = (const float*)d_in[13];
    const float* g3     = (const float*)d_in[14];
    const float* b3     = (const float*)d_in[15];
    const float* m3     = (const float*)d_in[16];
    const float* v3     = (const float*)d_in[17];
    const float* W2     = (const float*)d_in[18];
    const float* g4     = (const float*)d_in[19];
    const float* b4     = (const float*)d_in[20];
    const float* m4     = (const float*)d_in[21];
    const float* v4     = (const float*)d_in[22];

    char* ws = (char*)d_ws;
    float*          x_pm   = (float*)(ws + 0);                  // 25,690,112
    float*          x2_pm  = (float*)(ws + 25690112);           // 25,690,112
    unsigned short* x2_bf  = (unsigned short*)(ws + 51380224);  // 12,845,056
    unsigned short* qkv_pm = (unsigned short*)(ws + 64225280);  // 38,535,168
    unsigned short* msg_pm = (unsigned short*)(ws + 102760448); // 12,845,056
    unsigned short* t1     = (unsigned short*)(ws + 115605504); // 51,380,224 (h_bf aliases)
    unsigned short* h_bf   = t1;
    unsigned short* t2     = (unsigned short*)(ws + 166985728); // 51,380,224
    float*          ph     = (float*)(ws + 218365952);          // 524,288
    float*          qr     = (float*)(ws + 218890240);          // 524,288
    float*          kr     = (float*)(ws + 219414528);          // 524,288
    int*            idxb   = (int*)(ws + 219938816);            // 16,384
    unsigned short* Wqkv_b = (unsigned short*)(ws + 219955200); // 393,216
    unsigned short* Wmrg_b = (unsigned short*)(ws + 220348416); // 131,072
    unsigned short* W1_b   = (unsigned short*)(ws + 220479488); // 524,288
    unsigned short* W2_b   = (unsigned short*)(ws + 221003776); // 524,288
    if (ws_size < 221528064) return;

    cvt_all_k<<<3072, 256, 0, stream>>>(Wqkv, Wmerge, W1, W2, Wqkv_b, Wmrg_b, W1_b, W2_b);
    transin_k<<<dim3(49, 4, BB), 256, 0, stream>>>(x, g1, b1, m1, v1, x_pm, h_bf);
    // qkv = h . Wqkv^T (q pre-scaled)
    gemm_mfma_k<0, 128><<<dim3(196, 6), 512, 0, stream>>>(h_bf, Wqkv_b, 256, 768,
        qkv_pm, nullptr, nullptr, nullptr, nullptr, nullptr, nullptr);
    poolh_k<<<dim3(64, BB), 256, 0, stream>>>(x_pm, g1, b1, m1, v1, ph);
    qrkr_k<<<dim3(64, BB), 256, 0, stream>>>(ph, Wqkv, qr, kr);
    topk_k<<<dim3(64, BB), 64, 0, stream>>>(qr, kr, idxb);
    attn_mfma_k<<<dim3(64, 8, BB), 256, 0, stream>>>(qkv_pm, idxb, msg_pm);
    // x2 = x + msg . Wmerge^T + b_merge   (64-row tiles: 784 blocks, balanced)
    gemm_mfma_k<1, 64><<<dim3(392, 2), 256, 0, stream>>>(msg_pm, Wmrg_b, 256, 256,
        x2_pm, x2_bf, bmerge, nullptr, nullptr, nullptr, x_pm);
    // t1 = gelu(bn2(x2 . W1^T))
    gemm_mfma_k<2, 128><<<dim3(196, 8), 512, 0, stream>>>(x2_bf, W1_b, 256, 1024,
        t1, nullptr, g2, b2, m2, v2, nullptr);
    dwconv_k<<<dim3(49, 16, BB), 256, 0, stream>>>(t1, Wdw, g3, b3, m3, v3, t2);
    // d_out (NCHW) = x2 + bn4(t2 . W2^T)  (64-row tiles + fused transout)
    gemm_mfma_k<3, 64><<<dim3(392, 2), 256, 0, stream>>>(t2, W2_b, 1024, 256,
        (float*)d_out, nullptr, g4, b4, m4, v4, x2_pm);
}

// Round 14
// 298.269 us; speedup vs baseline: 1.0691x; 1.0691x over previous
//
#include <hip/hip_runtime.h>
#include <hip/hip_bf16.h>
#include <cstdint>
#include <cstddef>

#define BB 8
#define PP 3136
#define EPSV 1e-5f
#define SCQK 0.17677669529663687f

using bf16x8 = __attribute__((ext_vector_type(8))) short;
using f32x4  = __attribute__((ext_vector_type(4))) float;

__device__ __forceinline__ float bf2f(unsigned short u) {
    union { float f; unsigned int i; } c; c.i = ((unsigned int)u) << 16; return c.f;
}
__device__ __forceinline__ unsigned short f2bf(float f) {
    __hip_bfloat16 h = __float2bfloat16(f);
    union { __hip_bfloat16 h; unsigned short u; } c; c.h = h; return c.u;
}
__device__ __forceinline__ float gelu_f(float t) {
    return 0.5f * t * (1.0f + erff(t * 0.70710678118654752440f));
}
__device__ __forceinline__ float gelu_fast(float x) {
    float z = 1.5957691216057308f * (x + 0.044715f * x * x * x);
    return x / (1.0f + __expf(-z));
}
__device__ __forceinline__ void async16(const void* g, void* s) {
    __builtin_amdgcn_global_load_lds(
        (const __attribute__((address_space(1))) unsigned int*)g,
        (__attribute__((address_space(3))) unsigned int*)s, 16, 0, 0);
}
__device__ __forceinline__ uint4 pack8(const float* v) {
    uint4 o;
    o.x = (unsigned)f2bf(v[0]) | ((unsigned)f2bf(v[1]) << 16);
    o.y = (unsigned)f2bf(v[2]) | ((unsigned)f2bf(v[3]) << 16);
    o.z = (unsigned)f2bf(v[4]) | ((unsigned)f2bf(v[5]) << 16);
    o.w = (unsigned)f2bf(v[6]) | ((unsigned)f2bf(v[7]) << 16);
    return o;
}

// ---------- all weights f32 -> bf16, one launch ----------
__global__ __launch_bounds__(256) void cvt_all_k(
    const float* __restrict__ Wq, const float* __restrict__ Wm,
    const float* __restrict__ W1, const float* __restrict__ W2,
    unsigned short* __restrict__ dq, unsigned short* __restrict__ dm,
    unsigned short* __restrict__ d1, unsigned short* __restrict__ d2)
{
    int i = blockIdx.x * 256 + threadIdx.x;   // total 786432
    if (i < 196608) dq[i] = f2bf(Wq[i]);
    else if (i < 262144) dm[i - 196608] = f2bf(Wm[i - 196608]);
    else if (i < 524288) d1[i - 262144] = f2bf(W1[i - 262144]);
    else d2[i - 524288] = f2bf(W2[i - 524288]);
}

// ---------- transpose-in: x NCHW -> x_pm f32 [b][p][256] + h_bf bf16 (gelu(bn1)) ----------
__global__ __launch_bounds__(256) void transin_k(const float* __restrict__ x,
    const float* __restrict__ g1, const float* __restrict__ b1,
    const float* __restrict__ m1, const float* __restrict__ v1,
    float* __restrict__ x_pm, unsigned short* __restrict__ h_bf)
{
    __shared__ float tile[64][65];
    __shared__ float gam[64], bet[64], mu[64], rst[64];
    const int p0 = blockIdx.x * 64, c0 = blockIdx.y * 64, b = blockIdx.z;
    const int t = threadIdx.x;
    if (t < 64) { int c = c0 + t; gam[t] = g1[c]; bet[t] = b1[c]; mu[t] = m1[c]; rst[t] = rsqrtf(v1[c] + EPSV); }
    {
        int cl = t >> 2, px = (t & 3) * 16;
        const float* src = x + ((size_t)(b * 256 + c0 + cl)) * PP + p0 + px;
        #pragma unroll
        for (int i4 = 0; i4 < 4; i4++) {
            float4 r0 = *(const float4*)(src + i4 * 4);
            tile[cl][px + i4*4 + 0] = r0.x; tile[cl][px + i4*4 + 1] = r0.y;
            tile[cl][px + i4*4 + 2] = r0.z; tile[cl][px + i4*4 + 3] = r0.w;
        }
    }
    __syncthreads();
    {
        int pl = t >> 2, cb = (t & 3) * 16;
        float raw[16], hg[16];
        #pragma unroll
        for (int i = 0; i < 16; i++) {
            float vv = tile[cb + i][pl];
            raw[i] = vv;
            hg[i] = gelu_fast(gam[cb + i] * (vv - mu[cb + i]) * rst[cb + i] + bet[cb + i]);
        }
        size_t off = ((size_t)b * PP + p0 + pl) * 256 + c0 + cb;
        float* xd = x_pm + off;
        #pragma unroll
        for (int i4 = 0; i4 < 4; i4++) {
            float4 o; o.x = raw[i4*4]; o.y = raw[i4*4+1]; o.z = raw[i4*4+2]; o.w = raw[i4*4+3];
            *(float4*)(xd + i4 * 4) = o;
        }
        uint4* hd = (uint4*)(h_bf + off);
        hd[0] = pack8(&hg[0]);
        hd[1] = pack8(&hg[8]);
    }
}

// ---------- MFMA GEMM: D[flat_row][m] = sum_k A[flat_row][k] * W[m][k] ----------
// 128x128 tile, BK=32, 8 waves (512 thr, 2x4), global_load_lds(16B), 2-buf dbuf,
// XOR-swizzled LDS (both-sides). LDS 32KB -> 2 blocks/CU = 16 waves/CU.
// EPI 0: bf16 = acc (q cols scaled)   EPI 1: f32 = acc+bias+resid & bf16 copy
// EPI 2: bf16 = gelu_fast(bn(acc))    EPI 3: d_out NCHW f32 = bn(acc)+resid (fused transout)
template<int EPI>
__global__ __launch_bounds__(512) void gemm_mfma_k(
    const unsigned short* __restrict__ Aact,
    const unsigned short* __restrict__ Wbf,
    const int K, const int Mout,
    void* __restrict__ C1, void* __restrict__ C2,
    const float* __restrict__ e0, const float* __restrict__ e1,
    const float* __restrict__ e2, const float* __restrict__ e3,
    const float* __restrict__ resid)
{
    __shared__ __align__(16) char smem[32768];            // staging 32KB | T[32][132] 16.9KB
    unsigned short* As0 = (unsigned short*)smem;          // [2][128*32]
    unsigned short* Bs0 = (unsigned short*)(smem + 16384);// [2][128*32]
    float* T = (float*)smem;

    const int tid = threadIdx.x;                          // 0..511
    const int w = tid >> 6, lane = tid & 63, g = lane >> 4, l15 = lane & 15;
    const int wm = w >> 2, wn = w & 3;                    // 2 x 4 wave grid
    const size_t row0 = (size_t)blockIdx.x * 128;
    const int n0 = blockIdx.y * 128;
    const int srow = tid >> 2, scb = tid & 3;             // 1 A-unit + 1 B-unit per thread

    const f32x4 vzero = {0.f, 0.f, 0.f, 0.f};
    f32x4 acc[4][2];                                      // wave: 64 rows x 32 cols
    #pragma unroll
    for (int mf = 0; mf < 4; mf++)
        #pragma unroll
        for (int nf = 0; nf < 2; nf++) acc[mf][nf] = vzero;

    const int NT = K >> 5;
    const int cbp = scb ^ ((srow >> 1) & 3);              // inverse-swizzled source unit
    const int dstoff = (tid & ~63) * 8;                   // wave-uniform LDS base (elems)

    auto STAGE = [&](int s) {
        const int k0 = s << 5;
        async16(Aact + (row0 + srow) * K + k0 + cbp * 8, As0 + (s & 1) * 4096 + dstoff);
        async16(Wbf + (size_t)(n0 + srow) * K + k0 + cbp * 8, Bs0 + (s & 1) * 4096 + dstoff);
    };
    auto COMPUTE = [&](int t) {
        const unsigned short* Ab = As0 + (t & 1) * 4096;
        const unsigned short* Bb = Bs0 + (t & 1) * 4096;
        bf16x8 af[4], bfr[2];
        #pragma unroll
        for (int mf = 0; mf < 4; mf++) {
            int row = wm * 64 + mf * 16 + l15;
            int gb = g ^ ((row >> 1) & 3);
            af[mf] = *(const bf16x8*)&Ab[row * 32 + gb * 8];
        }
        #pragma unroll
        for (int nf = 0; nf < 2; nf++) {
            int row = wn * 32 + nf * 16 + l15;
            int gb = g ^ ((row >> 1) & 3);
            bfr[nf] = *(const bf16x8*)&Bb[row * 32 + gb * 8];
        }
        #pragma unroll
        for (int mf = 0; mf < 4; mf++)
            #pragma unroll
            for (int nf = 0; nf < 2; nf++)
                acc[mf][nf] = __builtin_amdgcn_mfma_f32_16x16x32_bf16(af[mf], bfr[nf], acc[mf][nf], 0, 0, 0);
    };

    STAGE(0);
    for (int t = 0; t < NT; ++t) {
        __syncthreads();                 // drains stage(t); buf (t-1) readers done
        if (t + 1 < NT) STAGE(t + 1);    // flies under COMPUTE(t)
        COMPUTE(t);
    }

    // ---- 4-pass LDS-transpose epilogue over 32-row slabs, T[32][132] ----
    __syncthreads();                     // all MFMA LDS reads done before T reuse
    const int erow = tid >> 4;           // 0..31
    const int col0 = (tid & 15) * 8;     // 0..120
    #pragma unroll
    for (int p = 0; p < 4; ++p) {
        if (p) __syncthreads();
        if (wm == (p >> 1)) {
            const int mfb = (p & 1) * 2;
            #pragma unroll
            for (int mo = 0; mo < 2; mo++)
                #pragma unroll
                for (int nf = 0; nf < 2; nf++)
                    #pragma unroll
                    for (int r = 0; r < 4; r++)
                        T[(mo * 16 + g * 4 + r) * 132 + wn * 32 + nf * 16 + l15] = acc[mfb + mo][nf][r];
        }
        __syncthreads();
        if (EPI == 3) {
            // step b: bn + resid row-major (coalesced), in-place on T
            {
                const size_t prow = row0 + p * 32 + erow;
                const size_t offr = prow * 256 + n0 + col0;
                #pragma unroll
                for (int i = 0; i < 2; i++) {
                    float4 v  = *(const float4*)&T[erow * 132 + col0 + i * 4];
                    float4 ga = *(const float4*)(e0 + n0 + col0 + i * 4);
                    float4 be = *(const float4*)(e1 + n0 + col0 + i * 4);
                    float4 mm = *(const float4*)(e2 + n0 + col0 + i * 4);
                    float4 vv = *(const float4*)(e3 + n0 + col0 + i * 4);
                    float4 rr = *(const float4*)(resid + offr + i * 4);
                    float4 o;
                    o.x = ga.x * (v.x - mm.x) * rsqrtf(vv.x + EPSV) + be.x + rr.x;
                    o.y = ga.y * (v.y - mm.y) * rsqrtf(vv.y + EPSV) + be.y + rr.y;
                    o.z = ga.z * (v.z - mm.z) * rsqrtf(vv.z + EPSV) + be.z + rr.z;
                    o.w = ga.w * (v.w - mm.w) * rsqrtf(vv.w + EPSV) + be.w + rr.w;
                    *(float4*)&T[erow * 132 + col0 + i * 4] = o;
                }
            }
            __syncthreads();
            // step c: NCHW store — 256 threads, one (m, 16-p slab) each, 64B lines
            if (tid < 256) {
                const int m = tid & 127, ph2 = tid >> 7;
                const int prow16 = (int)row0 + p * 32 + ph2 * 16;
                const int bimg = prow16 / PP;         // 16-aligned slab stays in one image
                const int pp = prow16 - bimg * PP;
                float* dst = (float*)C1 + ((size_t)(bimg * 256 + n0 + m)) * PP + pp;
                #pragma unroll
                for (int i = 0; i < 4; i++) {
                    float4 o;
                    o.x = T[(ph2 * 16 + i * 4 + 0) * 132 + m];
                    o.y = T[(ph2 * 16 + i * 4 + 1) * 132 + m];
                    o.z = T[(ph2 * 16 + i * 4 + 2) * 132 + m];
                    o.w = T[(ph2 * 16 + i * 4 + 3) * 132 + m];
                    *(float4*)(dst + i * 4) = o;
                }
            }
        } else {
            float vals[8];
            #pragma unroll
            for (int i = 0; i < 2; i++) {
                float4 v = *(const float4*)&T[erow * 132 + col0 + i * 4];
                vals[i*4+0] = v.x; vals[i*4+1] = v.y; vals[i*4+2] = v.z; vals[i*4+3] = v.w;
            }
            const size_t prow = row0 + p * 32 + erow;
            const int mc0 = n0 + col0;
            const size_t off = prow * Mout + mc0;
            if (EPI == 0) {
                const float s = (mc0 < 256) ? SCQK : 1.0f;
                #pragma unroll
                for (int j = 0; j < 8; j++) vals[j] *= s;
                *(uint4*)((unsigned short*)C1 + off) = pack8(vals);
            } else if (EPI == 1) {
                #pragma unroll
                for (int i = 0; i < 2; i++) {
                    float4 bi = *(const float4*)(e0 + mc0 + i * 4);
                    float4 rr = *(const float4*)(resid + off + i * 4);
                    vals[i*4+0] += bi.x + rr.x; vals[i*4+1] += bi.y + rr.y;
                    vals[i*4+2] += bi.z + rr.z; vals[i*4+3] += bi.w + rr.w;
                }
                float4* d1 = (float4*)((float*)C1 + off);
                #pragma unroll
                for (int i = 0; i < 2; i++) {
                    float4 o; o.x = vals[i*4]; o.y = vals[i*4+1]; o.z = vals[i*4+2]; o.w = vals[i*4+3];
                    d1[i] = o;
                }
                *(uint4*)((unsigned short*)C2 + off) = pack8(vals);
            } else {  // EPI == 2
                #pragma unroll
                for (int i = 0; i < 2; i++) {
                    float4 ga = *(const float4*)(e0 + mc0 + i * 4);
                    float4 be = *(const float4*)(e1 + mc0 + i * 4);
                    float4 mm = *(const float4*)(e2 + mc0 + i * 4);
                    float4 vv = *(const float4*)(e3 + mc0 + i * 4);
                    vals[i*4+0] = gelu_fast(ga.x * (vals[i*4+0] - mm.x) * rsqrtf(vv.x + EPSV) + be.x);
                    vals[i*4+1] = gelu_fast(ga.y * (vals[i*4+1] - mm.y) * rsqrtf(vv.y + EPSV) + be.y);
                    vals[i*4+2] = gelu_fast(ga.z * (vals[i*4+2] - mm.z) * rsqrtf(vv.z + EPSV) + be.z);
                    vals[i*4+3] = gelu_fast(ga.w * (vals[i*4+3] - mm.w) * rsqrtf(vv.w + EPSV) + be.w);
                }
                *(uint4*)((unsigned short*)C1 + off) = pack8(vals);
            }
        }
    }
}

// ---------- exact-f32 window pooling of h (recomputed from x_pm) ----------
__global__ __launch_bounds__(256) void poolh_k(const float* __restrict__ x_pm,
    const float* __restrict__ g1, const float* __restrict__ b1,
    const float* __restrict__ m1, const float* __restrict__ v1,
    float* __restrict__ ph)
{
    __shared__ float part[4][256];
    __shared__ float gam[256], bet[256], mu[256], rst[256];
    const int n = blockIdx.x, b = blockIdx.y, t = threadIdx.x;
    gam[t] = g1[t]; bet[t] = b1[t]; mu[t] = m1[t]; rst[t] = rsqrtf(v1[t] + EPSV);
    __syncthreads();
    const int c4 = (t & 63) * 4, pg = t >> 6;
    float s0 = 0.f, s1 = 0.f, s2 = 0.f, s3 = 0.f;
    for (int j = pg; j < 49; j += 4) {
        int p = ((n >> 3) * 7 + j / 7) * 56 + (n & 7) * 7 + j % 7;
        float4 vx = *(const float4*)(x_pm + ((size_t)b * PP + p) * 256 + c4);
        s0 += gelu_f(gam[c4+0] * (vx.x - mu[c4+0]) * rst[c4+0] + bet[c4+0]);
        s1 += gelu_f(gam[c4+1] * (vx.y - mu[c4+1]) * rst[c4+1] + bet[c4+1]);
        s2 += gelu_f(gam[c4+2] * (vx.z - mu[c4+2]) * rst[c4+2] + bet[c4+2]);
        s3 += gelu_f(gam[c4+3] * (vx.w - mu[c4+3]) * rst[c4+3] + bet[c4+3]);
    }
    part[pg][c4 + 0] = s0; part[pg][c4 + 1] = s1; part[pg][c4 + 2] = s2; part[pg][c4 + 3] = s3;
    __syncthreads();
    float tot = part[0][t] + part[1][t] + part[2][t] + part[3][t];
    ph[((size_t)b * 64 + n) * 256 + t] = tot * (1.0f / 49.0f);
}

// ---------- qr/kr = poolh . Wq^T / Wk^T (f32 exact) ----------
__global__ __launch_bounds__(256) void qrkr_k(const float* __restrict__ ph,
    const float* __restrict__ Wqkv, float* __restrict__ qr, float* __restrict__ kr)
{
    __shared__ float row[256];
    const int n = blockIdx.x, b = blockIdx.y, t = threadIdx.x;
    row[t] = ph[((size_t)b * 64 + n) * 256 + t];
    __syncthreads();
    const float* wq = Wqkv + (size_t)t * 256;
    const float* wk = Wqkv + (size_t)(256 + t) * 256;
    float aq = 0.f, ak = 0.f;
    #pragma unroll 4
    for (int k = 0; k < 256; k += 4) {
        float4 a4 = *(const float4*)(wq + k);
        float4 b4 = *(const float4*)(wk + k);
        aq += row[k]*a4.x + row[k+1]*a4.y + row[k+2]*a4.z + row[k+3]*a4.w;
        ak += row[k]*b4.x + row[k+1]*b4.y + row[k+2]*b4.z + row[k+3]*b4.w;
    }
    qr[((size_t)b * 64 + n) * 256 + t] = aq;
    kr[((size_t)b * 64 + n) * 256 + t] = ak;
}

// ---------- aff row + top-8 (one wave per (b,n)) ----------
__global__ __launch_bounds__(64) void topk_k(const float* __restrict__ qr,
    const float* __restrict__ kr, int* __restrict__ idxb)
{
    const int n = blockIdx.x, b_ = blockIdx.y;
    const int tid = threadIdx.x;
    __shared__ float qrow[256];
    *reinterpret_cast<float4*>(&qrow[tid * 4]) =
        *reinterpret_cast<const float4*>(qr + ((size_t)(b_ * 64) + n) * 256 + tid * 4);
    __syncthreads();
    const float* kp = kr + ((size_t)(b_ * 64) + tid) * 256;
    float av = 0.f;
    #pragma unroll 4
    for (int c = 0; c < 256; c++) av = fmaf(qrow[c], kp[c], av);
    for (int t = 0; t < 8; t++) {
        float v = av; int id = tid;
        #pragma unroll
        for (int off = 32; off; off >>= 1) {
            float v2 = __shfl_xor(v, off);
            int id2 = __shfl_xor(id, off);
            if (v2 > v || (v2 == v && id2 < id)) { v = v2; id = id2; }
        }
        if (tid == 0) idxb[((b_ * 64) + n) * 8 + t] = id;
        if (tid == id) av = -1e30f;
    }
}

// ---------- MFMA flash attention: fixed-shift softmax + Pr LDS + s_setprio (T5) ----------
__global__ __launch_bounds__(256) void attn_mfma_k(const unsigned short* __restrict__ qkv,
    const int* __restrict__ idxb, unsigned short* __restrict__ msg)
{
    __shared__ __align__(16) unsigned short Ks[64 * 40];
    __shared__ __align__(16) unsigned short Vt[32 * 72];
    __shared__ __align__(16) unsigned short Pr[4][16 * 72];
    const int n = blockIdx.x, h = blockIdx.y, b = blockIdx.z;
    const int tid = threadIdx.x;
    const int w = tid >> 6, lane = tid & 63, g = lane >> 4, l15 = lane & 15;

    for (int e = tid; e < 64 * 40; e += 256) Ks[e] = 0;
    for (int e = tid; e < 32 * 72; e += 256) Vt[e] = 0;

    const int iq = w * 16 + l15;
    bf16x8 qf = {0, 0, 0, 0, 0, 0, 0, 0};
    if (iq < 49) {
        int p = ((n >> 3) * 7 + iq / 7) * 56 + (n & 7) * 7 + iq % 7;
        qf = *(const bf16x8*)(qkv + ((size_t)b * PP + p) * 768 + h * 32 + g * 8);
    }
    int widx[8];
    {
        const int* ip = idxb + ((b * 64) + n) * 8;
        #pragma unroll
        for (int t = 0; t < 8; t++) widx[t] = ip[t];
    }
    const f32x4 vzero = {0.f, 0.f, 0.f, 0.f};
    f32x4 o0 = vzero, o1 = vzero;
    float lsum = 0.f;

    const bool act = tid < 196;
    const int jrow = tid >> 2, c8 = (tid & 3) * 8;
    uint4 kk_r = {0,0,0,0}, vv_r = {0,0,0,0};
    auto LOADW = [&](int t) {
        int wsrc = widx[t];
        int p = ((wsrc >> 3) * 7 + jrow / 7) * 56 + (wsrc & 7) * 7 + jrow % 7;
        const unsigned short* srcp = qkv + ((size_t)b * PP + p) * 768 + 256 + h * 32 + c8;
        kk_r = *(const uint4*)srcp;
        vv_r = *(const uint4*)(srcp + 256);
    };
    if (act) LOADW(0);

    for (int t = 0; t < 8; t++) {
        __syncthreads();
        if (act) {
            *(uint4*)&Ks[jrow * 40 + c8] = kk_r;
            const unsigned short* pv = (const unsigned short*)&vv_r;
            #pragma unroll
            for (int jj = 0; jj < 8; jj++) {
                int dh = c8 + jj;
                Vt[dh * 72 + (jrow ^ (((dh >> 3) & 3) << 3))] = pv[jj];
            }
            if (t < 7) LOADW(t + 1);
        }
        __syncthreads();
        __builtin_amdgcn_s_setprio(1);
        f32x4 s[4];
        #pragma unroll
        for (int nf = 0; nf < 4; nf++) {
            bf16x8 kf = *(const bf16x8*)&Ks[(nf * 16 + l15) * 40 + g * 8];
            s[nf] = __builtin_amdgcn_mfma_f32_16x16x32_bf16(kf, qf, vzero, 0, 0, 0);
        }
        __builtin_amdgcn_s_setprio(0);
        float pe[16];
        #pragma unroll
        for (int nf = 0; nf < 4; nf++)
            #pragma unroll
            for (int r = 0; r < 4; r++) {
                int j = nf * 16 + g * 4 + r;
                float e_ = __expf(s[nf][r] - 10.0f);
                float pv_ = (j < 49) ? e_ : 0.f;
                pe[nf * 4 + r] = pv_;
                lsum += pv_;
            }
        #pragma unroll
        for (int nf = 0; nf < 4; nf++) {
            uint2 pw;
            pw.x = (unsigned)f2bf(pe[nf*4+0]) | ((unsigned)f2bf(pe[nf*4+1]) << 16);
            pw.y = (unsigned)f2bf(pe[nf*4+2]) | ((unsigned)f2bf(pe[nf*4+3]) << 16);
            *(uint2*)&Pr[w][l15 * 72 + nf * 16 + g * 4] = pw;
        }
        asm volatile("s_waitcnt lgkmcnt(0)" ::: "memory");
        __builtin_amdgcn_sched_barrier(0);
        __builtin_amdgcn_s_setprio(1);
        #pragma unroll
        for (int ks = 0; ks < 2; ks++) {
            const int j0 = ks * 32 + g * 8;
            bf16x8 pf  = *(const bf16x8*)&Pr[w][l15 * 72 + j0];
            bf16x8 vf0 = *(const bf16x8*)&Vt[l15 * 72 + (j0 ^ (((l15 >> 3) & 1) << 3))];
            bf16x8 vf1 = *(const bf16x8*)&Vt[(16 + l15) * 72 + (j0 ^ ((2 + (l15 >> 3)) << 3))];
            o0 = __builtin_amdgcn_mfma_f32_16x16x32_bf16(vf0, pf, o0, 0, 0, 0);
            o1 = __builtin_amdgcn_mfma_f32_16x16x32_bf16(vf1, pf, o1, 0, 0, 0);
        }
        __builtin_amdgcn_s_setprio(0);
    }
    lsum += __shfl_xor(lsum, 16);
    lsum += __shfl_xor(lsum, 32);
    if (iq < 49) {
        float inv = 1.0f / lsum;
        int p = ((n >> 3) * 7 + iq / 7) * 56 + (n & 7) * 7 + iq % 7;
        size_t off = ((size_t)b * PP + p) * 256 + h * 32;
        uint2 w0, w1;
        w0.x = (unsigned)f2bf(o0[0]*inv) | ((unsigned)f2bf(o0[1]*inv) << 16);
        w0.y = (unsigned)f2bf(o0[2]*inv) | ((unsigned)f2bf(o0[3]*inv) << 16);
        w1.x = (unsigned)f2bf(o1[0]*inv) | ((unsigned)f2bf(o1[1]*inv) << 16);
        w1.y = (unsigned)f2bf(o1[2]*inv) | ((unsigned)f2bf(o1[3]*inv) << 16);
        *(uint2*)(msg + off + g * 4) = w0;
        *(uint2*)(msg + off + 16 + g * 4) = w1;
    }
}

// ---------- depthwise 3x3 + bn3 + gelu, position-major ----------
__global__ __launch_bounds__(256) void dwconv_k(const unsigned short* __restrict__ in,
    const float* __restrict__ w9,
    const float* __restrict__ g3, const float* __restrict__ b3,
    const float* __restrict__ m3, const float* __restrict__ v3,
    unsigned short* __restrict__ out)
{
    __shared__ __align__(16) unsigned short tl[100 * 64];
    const int sx = blockIdx.x % 7, sy = blockIdx.x / 7;
    const int c0 = blockIdx.y * 64, b = blockIdx.z;
    const int t = threadIdx.x;
    for (int e = t; e < 800; e += 256) {
        int pos = e >> 3, c8 = (e & 7) * 8;
        int iy = sy * 8 + pos / 10 - 1, ix = sx * 8 + pos % 10 - 1;
        uint4 val = {0u, 0u, 0u, 0u};
        if (iy >= 0 && iy < 56 && ix >= 0 && ix < 56)
            val = *(const uint4*)(in + ((size_t)b * PP + iy * 56 + ix) * 1024 + c0 + c8);
        *(uint4*)&tl[pos * 64 + c8] = val;
    }
    __syncthreads();
    const int c2 = (t & 31) * 2, pg = t >> 5;
    const int c = c0 + c2;
    float w0[9], w1[9];
    #pragma unroll
    for (int i = 0; i < 9; i++) { w0[i] = w9[c * 9 + i]; w1[i] = w9[(c + 1) * 9 + i]; }
    const float ga0 = g3[c], be0 = b3[c], mu0 = m3[c], rs0 = rsqrtf(v3[c] + EPSV);
    const float ga1 = g3[c+1], be1 = b3[c+1], mu1 = m3[c+1], rs1 = rsqrtf(v3[c+1] + EPSV);
    #pragma unroll
    for (int q = 0; q < 8; q++) {
        int pos = pg * 8 + q, y = pos >> 3, xq = pos & 7;
        float s0 = 0.f, s1 = 0.f;
        #pragma unroll
        for (int dy = 0; dy < 3; dy++)
            #pragma unroll
            for (int dx = 0; dx < 3; dx++) {
                unsigned int u = *(const unsigned int*)&tl[((y + dy) * 10 + xq + dx) * 64 + c2];
                s0 = fmaf(bf2f((unsigned short)(u & 0xffffu)), w0[dy * 3 + dx], s0);
                s1 = fmaf(bf2f((unsigned short)(u >> 16)), w1[dy * 3 + dx], s1);
            }
        float y0 = gelu_fast(ga0 * (s0 - mu0) * rs0 + be0);
        float y1 = gelu_fast(ga1 * (s1 - mu1) * rs1 + be1);
        unsigned int ow = (unsigned int)f2bf(y0) | ((unsigned int)f2bf(y1) << 16);
        size_t off = ((size_t)b * PP + (sy * 8 + y) * 56 + sx * 8 + xq) * 1024 + c;
        *(unsigned int*)&out[off] = ow;
    }
}

// ---------- launch ----------
extern "C" void kernel_launch(void* const* d_in, const int* in_sizes, int n_in,
                              void* d_out, int out_size, void* d_ws, size_t ws_size,
                              hipStream_t stream)
{
    const float* x      = (const float*)d_in[0];
    const float* g1     = (const float*)d_in[1];
    const float* b1     = (const float*)d_in[2];
    const float* m1     = (const float*)d_in[3];
    const float* v1     = (const float*)d_in[4];
    const float* Wqkv   = (const float*)d_in[5];
    const float* Wmerge = (const float*)d_in[6];
    const float* bmerge = (const float*)d_in[7];
    const float* W1     = (const float*)d_in[8];
    const float* g2     = (const float*)d_in[9];
    const float* b2     = (const float*)d_in[10];
    const float* m2     = (const float*)d_in[11];
    const float* v2     = (const float*)d_in[12];
    const float* Wdw    = (const float*)d_in[13];
    const float* g3     = (const float*)d_in[14];
    const float* b3     = (const float*)d_in[15];
    const float* m3     = (const float*)d_in[16];
    const float* v3     = (const float*)d_in[17];
    const float* W2     = (const float*)d_in[18];
    const float* g4     = (const float*)d_in[19];
    const float* b4     = (const float*)d_in[20];
    const float* m4     = (const float*)d_in[21];
    const float* v4     = (const float*)d_in[22];

    char* ws = (char*)d_ws;
    float*          x_pm   = (float*)(ws + 0);                  // 25,690,112
    float*          x2_pm  = (float*)(ws + 25690112);           // 25,690,112
    unsigned short* x2_bf  = (unsigned short*)(ws + 51380224);  // 12,845,056
    unsigned short* qkv_pm = (unsigned short*)(ws + 64225280);  // 38,535,168
    unsigned short* msg_pm = (unsigned short*)(ws + 102760448); // 12,845,056
    unsigned short* t1     = (unsigned short*)(ws + 115605504); // 51,380,224 (h_bf aliases)
    unsigned short* h_bf   = t1;
    unsigned short* t2     = (unsigned short*)(ws + 166985728); // 51,380,224
    float*          ph     = (float*)(ws + 218365952);          // 524,288
    float*          qr     = (float*)(ws + 218890240);          // 524,288
    float*          kr     = (float*)(ws + 219414528);          // 524,288
    int*            idxb   = (int*)(ws + 219938816);            // 16,384
    unsigned short* Wqkv_b = (unsigned short*)(ws + 219955200); // 393,216
    unsigned short* Wmrg_b = (unsigned short*)(ws + 220348416); // 131,072
    unsigned short* W1_b   = (unsigned short*)(ws + 220479488); // 524,288
    unsigned short* W2_b   = (unsigned short*)(ws + 221003776); // 524,288
    if (ws_size < 221528064) return;

    cvt_all_k<<<3072, 256, 0, stream>>>(Wqkv, Wmerge, W1, W2, Wqkv_b, Wmrg_b, W1_b, W2_b);
    transin_k<<<dim3(49, 4, BB), 256, 0, stream>>>(x, g1, b1, m1, v1, x_pm, h_bf);
    // qkv = h . Wqkv^T (q pre-scaled)
    gemm_mfma_k<0><<<dim3(196, 6), 512, 0, stream>>>(h_bf, Wqkv_b, 256, 768,
        qkv_pm, nullptr, nullptr, nullptr, nullptr, nullptr, nullptr);
    poolh_k<<<dim3(64, BB), 256, 0, stream>>>(x_pm, g1, b1, m1, v1, ph);
    qrkr_k<<<dim3(64, BB), 256, 0, stream>>>(ph, Wqkv, qr, kr);
    topk_k<<<dim3(64, BB), 64, 0, stream>>>(qr, kr, idxb);
    attn_mfma_k<<<dim3(64, 8, BB), 256, 0, stream>>>(qkv_pm, idxb, msg_pm);
    // x2 = x + msg . Wmerge^T + b_merge
    gemm_mfma_k<1><<<dim3(196, 2), 512, 0, stream>>>(msg_pm, Wmrg_b, 256, 256,
        x2_pm, x2_bf, bmerge, nullptr, nullptr, nullptr, x_pm);
    // t1 = gelu(bn2(x2 . W1^T))
    gemm_mfma_k<2><<<dim3(196, 8), 512, 0, stream>>>(x2_bf, W1_b, 256, 1024,
        t1, nullptr, g2, b2, m2, v2, nullptr);
    dwconv_k<<<dim3(49, 16, BB), 256, 0, stream>>>(t1, Wdw, g3, b3, m3, v3, t2);
    // d_out (NCHW) = x2 + bn4(t2 . W2^T)  — transout fused into epilogue
    gemm_mfma_k<3><<<dim3(196, 2), 512, 0, stream>>>(t2, W2_b, 1024, 256,
        (float*)d_out, nullptr, g4, b4, m4, v4, x2_pm);
}

// Round 15
// 292.230 us; speedup vs baseline: 1.0912x; 1.0207x over previous
//
#include <hip/hip_runtime.h>
#include <hip/hip_bf16.h>
#include <cstdint>
#include <cstddef>

#define BB 8
#define PP 3136
#define EPSV 1e-5f
#define SCQK 0.17677669529663687f

using bf16x8 = __attribute__((ext_vector_type(8))) short;
using f32x4  = __attribute__((ext_vector_type(4))) float;

__device__ __forceinline__ float bf2f(unsigned short u) {
    union { float f; unsigned int i; } c; c.i = ((unsigned int)u) << 16; return c.f;
}
__device__ __forceinline__ unsigned short f2bf(float f) {
    __hip_bfloat16 h = __float2bfloat16(f);
    union { __hip_bfloat16 h; unsigned short u; } c; c.h = h; return c.u;
}
__device__ __forceinline__ float gelu_f(float t) {
    return 0.5f * t * (1.0f + erff(t * 0.70710678118654752440f));
}
__device__ __forceinline__ float gelu_fast(float x) {
    float z = 1.5957691216057308f * (x + 0.044715f * x * x * x);
    return x / (1.0f + __expf(-z));
}
__device__ __forceinline__ void async16(const void* g, void* s) {
    __builtin_amdgcn_global_load_lds(
        (const __attribute__((address_space(1))) unsigned int*)g,
        (__attribute__((address_space(3))) unsigned int*)s, 16, 0, 0);
}
__device__ __forceinline__ uint4 pack8(const float* v) {
    uint4 o;
    o.x = (unsigned)f2bf(v[0]) | ((unsigned)f2bf(v[1]) << 16);
    o.y = (unsigned)f2bf(v[2]) | ((unsigned)f2bf(v[3]) << 16);
    o.z = (unsigned)f2bf(v[4]) | ((unsigned)f2bf(v[5]) << 16);
    o.w = (unsigned)f2bf(v[6]) | ((unsigned)f2bf(v[7]) << 16);
    return o;
}

// ---------- all weights f32 -> bf16, one launch ----------
__global__ __launch_bounds__(256) void cvt_all_k(
    const float* __restrict__ Wq, const float* __restrict__ Wm,
    const float* __restrict__ W1, const float* __restrict__ W2,
    unsigned short* __restrict__ dq, unsigned short* __restrict__ dm,
    unsigned short* __restrict__ d1, unsigned short* __restrict__ d2)
{
    int i = blockIdx.x * 256 + threadIdx.x;   // total 786432
    if (i < 196608) dq[i] = f2bf(Wq[i]);
    else if (i < 262144) dm[i - 196608] = f2bf(Wm[i - 196608]);
    else if (i < 524288) d1[i - 262144] = f2bf(W1[i - 262144]);
    else d2[i - 524288] = f2bf(W2[i - 524288]);
}

// ---------- transpose-in: x NCHW -> x_pm f32 [b][p][256] + h_bf bf16 (gelu(bn1)) ----------
__global__ __launch_bounds__(256) void transin_k(const float* __restrict__ x,
    const float* __restrict__ g1, const float* __restrict__ b1,
    const float* __restrict__ m1, const float* __restrict__ v1,
    float* __restrict__ x_pm, unsigned short* __restrict__ h_bf)
{
    __shared__ float tile[64][65];
    __shared__ float gam[64], bet[64], mu[64], rst[64];
    const int p0 = blockIdx.x * 64, c0 = blockIdx.y * 64, b = blockIdx.z;
    const int t = threadIdx.x;
    if (t < 64) { int c = c0 + t; gam[t] = g1[c]; bet[t] = b1[c]; mu[t] = m1[c]; rst[t] = rsqrtf(v1[c] + EPSV); }
    {
        int cl = t >> 2, px = (t & 3) * 16;
        const float* src = x + ((size_t)(b * 256 + c0 + cl)) * PP + p0 + px;
        #pragma unroll
        for (int i4 = 0; i4 < 4; i4++) {
            float4 r0 = *(const float4*)(src + i4 * 4);
            tile[cl][px + i4*4 + 0] = r0.x; tile[cl][px + i4*4 + 1] = r0.y;
            tile[cl][px + i4*4 + 2] = r0.z; tile[cl][px + i4*4 + 3] = r0.w;
        }
    }
    __syncthreads();
    {
        int pl = t >> 2, cb = (t & 3) * 16;
        float raw[16], hg[16];
        #pragma unroll
        for (int i = 0; i < 16; i++) {
            float vv = tile[cb + i][pl];
            raw[i] = vv;
            hg[i] = gelu_fast(gam[cb + i] * (vv - mu[cb + i]) * rst[cb + i] + bet[cb + i]);
        }
        size_t off = ((size_t)b * PP + p0 + pl) * 256 + c0 + cb;
        float* xd = x_pm + off;
        #pragma unroll
        for (int i4 = 0; i4 < 4; i4++) {
            float4 o; o.x = raw[i4*4]; o.y = raw[i4*4+1]; o.z = raw[i4*4+2]; o.w = raw[i4*4+3];
            *(float4*)(xd + i4 * 4) = o;
        }
        uint4* hd = (uint4*)(h_bf + off);
        hd[0] = pack8(&hg[0]);
        hd[1] = pack8(&hg[8]);
    }
}

// ---------- MFMA GEMM: D[flat_row][m] = sum_k A[flat_row][k] * W[m][k] ----------
// 128x128 tile, BK=32, 8 waves (512 thr, 2x4), global_load_lds(16B), 2-buf dbuf,
// XOR-swizzled LDS (both-sides). LDS 32KB -> 2 blocks/CU = 16 waves/CU.
// EPI 0: bf16 = acc (q cols scaled)   EPI 1: f32 = acc+bias+resid & bf16 copy
// EPI 2: bf16 = gelu_fast(bn(acc))    EPI 3: d_out NCHW f32 = bn(acc)+resid (fused transout)
template<int EPI>
__global__ __launch_bounds__(512) void gemm_mfma_k(
    const unsigned short* __restrict__ Aact,
    const unsigned short* __restrict__ Wbf,
    const int K, const int Mout,
    void* __restrict__ C1, void* __restrict__ C2,
    const float* __restrict__ e0, const float* __restrict__ e1,
    const float* __restrict__ e2, const float* __restrict__ e3,
    const float* __restrict__ resid)
{
    __shared__ __align__(16) char smem[32768];            // staging 32KB | T[32][132] 16.9KB
    unsigned short* As0 = (unsigned short*)smem;          // [2][128*32]
    unsigned short* Bs0 = (unsigned short*)(smem + 16384);// [2][128*32]
    float* T = (float*)smem;

    const int tid = threadIdx.x;                          // 0..511
    const int w = tid >> 6, lane = tid & 63, g = lane >> 4, l15 = lane & 15;
    const int wm = w >> 2, wn = w & 3;                    // 2 x 4 wave grid
    const size_t row0 = (size_t)blockIdx.x * 128;
    const int n0 = blockIdx.y * 128;
    const int srow = tid >> 2, scb = tid & 3;             // 1 A-unit + 1 B-unit per thread

    const f32x4 vzero = {0.f, 0.f, 0.f, 0.f};
    f32x4 acc[4][2];                                      // wave: 64 rows x 32 cols
    #pragma unroll
    for (int mf = 0; mf < 4; mf++)
        #pragma unroll
        for (int nf = 0; nf < 2; nf++) acc[mf][nf] = vzero;

    const int NT = K >> 5;
    const int cbp = scb ^ ((srow >> 1) & 3);              // inverse-swizzled source unit
    const int dstoff = (tid & ~63) * 8;                   // wave-uniform LDS base (elems)

    auto STAGE = [&](int s) {
        const int k0 = s << 5;
        async16(Aact + (row0 + srow) * K + k0 + cbp * 8, As0 + (s & 1) * 4096 + dstoff);
        async16(Wbf + (size_t)(n0 + srow) * K + k0 + cbp * 8, Bs0 + (s & 1) * 4096 + dstoff);
    };
    auto COMPUTE = [&](int t) {
        const unsigned short* Ab = As0 + (t & 1) * 4096;
        const unsigned short* Bb = Bs0 + (t & 1) * 4096;
        bf16x8 af[4], bfr[2];
        #pragma unroll
        for (int mf = 0; mf < 4; mf++) {
            int row = wm * 64 + mf * 16 + l15;
            int gb = g ^ ((row >> 1) & 3);
            af[mf] = *(const bf16x8*)&Ab[row * 32 + gb * 8];
        }
        #pragma unroll
        for (int nf = 0; nf < 2; nf++) {
            int row = wn * 32 + nf * 16 + l15;
            int gb = g ^ ((row >> 1) & 3);
            bfr[nf] = *(const bf16x8*)&Bb[row * 32 + gb * 8];
        }
        #pragma unroll
        for (int mf = 0; mf < 4; mf++)
            #pragma unroll
            for (int nf = 0; nf < 2; nf++)
                acc[mf][nf] = __builtin_amdgcn_mfma_f32_16x16x32_bf16(af[mf], bfr[nf], acc[mf][nf], 0, 0, 0);
    };

    STAGE(0);
    for (int t = 0; t < NT; ++t) {
        __syncthreads();                 // drains stage(t); buf (t-1) readers done
        if (t + 1 < NT) STAGE(t + 1);    // flies under COMPUTE(t)
        COMPUTE(t);
    }

    // ---- 4-pass LDS-transpose epilogue over 32-row slabs, T[32][132] ----
    __syncthreads();                     // all MFMA LDS reads done before T reuse
    const int erow = tid >> 4;           // 0..31
    const int col0 = (tid & 15) * 8;     // 0..120
    #pragma unroll
    for (int p = 0; p < 4; ++p) {
        if (p) __syncthreads();
        if (wm == (p >> 1)) {
            const int mfb = (p & 1) * 2;
            #pragma unroll
            for (int mo = 0; mo < 2; mo++)
                #pragma unroll
                for (int nf = 0; nf < 2; nf++)
                    #pragma unroll
                    for (int r = 0; r < 4; r++)
                        T[(mo * 16 + g * 4 + r) * 132 + wn * 32 + nf * 16 + l15] = acc[mfb + mo][nf][r];
        }
        __syncthreads();
        if (EPI == 3) {
            // step b: bn + resid row-major (coalesced), in-place on T
            {
                const size_t prow = row0 + p * 32 + erow;
                const size_t offr = prow * 256 + n0 + col0;
                #pragma unroll
                for (int i = 0; i < 2; i++) {
                    float4 v  = *(const float4*)&T[erow * 132 + col0 + i * 4];
                    float4 ga = *(const float4*)(e0 + n0 + col0 + i * 4);
                    float4 be = *(const float4*)(e1 + n0 + col0 + i * 4);
                    float4 mm = *(const float4*)(e2 + n0 + col0 + i * 4);
                    float4 vv = *(const float4*)(e3 + n0 + col0 + i * 4);
                    float4 rr = *(const float4*)(resid + offr + i * 4);
                    float4 o;
                    o.x = ga.x * (v.x - mm.x) * rsqrtf(vv.x + EPSV) + be.x + rr.x;
                    o.y = ga.y * (v.y - mm.y) * rsqrtf(vv.y + EPSV) + be.y + rr.y;
                    o.z = ga.z * (v.z - mm.z) * rsqrtf(vv.z + EPSV) + be.z + rr.z;
                    o.w = ga.w * (v.w - mm.w) * rsqrtf(vv.w + EPSV) + be.w + rr.w;
                    *(float4*)&T[erow * 132 + col0 + i * 4] = o;
                }
            }
            __syncthreads();
            // step c: NCHW store — 256 threads, one (m, 16-p slab) each, 64B lines
            if (tid < 256) {
                const int m = tid & 127, ph2 = tid >> 7;
                const int prow16 = (int)row0 + p * 32 + ph2 * 16;
                const int bimg = prow16 / PP;         // 16-aligned slab stays in one image
                const int pp = prow16 - bimg * PP;
                float* dst = (float*)C1 + ((size_t)(bimg * 256 + n0 + m)) * PP + pp;
                #pragma unroll
                for (int i = 0; i < 4; i++) {
                    float4 o;
                    o.x = T[(ph2 * 16 + i * 4 + 0) * 132 + m];
                    o.y = T[(ph2 * 16 + i * 4 + 1) * 132 + m];
                    o.z = T[(ph2 * 16 + i * 4 + 2) * 132 + m];
                    o.w = T[(ph2 * 16 + i * 4 + 3) * 132 + m];
                    *(float4*)(dst + i * 4) = o;
                }
            }
        } else {
            float vals[8];
            #pragma unroll
            for (int i = 0; i < 2; i++) {
                float4 v = *(const float4*)&T[erow * 132 + col0 + i * 4];
                vals[i*4+0] = v.x; vals[i*4+1] = v.y; vals[i*4+2] = v.z; vals[i*4+3] = v.w;
            }
            const size_t prow = row0 + p * 32 + erow;
            const int mc0 = n0 + col0;
            const size_t off = prow * Mout + mc0;
            if (EPI == 0) {
                const float s = (mc0 < 256) ? SCQK : 1.0f;
                #pragma unroll
                for (int j = 0; j < 8; j++) vals[j] *= s;
                *(uint4*)((unsigned short*)C1 + off) = pack8(vals);
            } else if (EPI == 1) {
                #pragma unroll
                for (int i = 0; i < 2; i++) {
                    float4 bi = *(const float4*)(e0 + mc0 + i * 4);
                    float4 rr = *(const float4*)(resid + off + i * 4);
                    vals[i*4+0] += bi.x + rr.x; vals[i*4+1] += bi.y + rr.y;
                    vals[i*4+2] += bi.z + rr.z; vals[i*4+3] += bi.w + rr.w;
                }
                float4* d1 = (float4*)((float*)C1 + off);
                #pragma unroll
                for (int i = 0; i < 2; i++) {
                    float4 o; o.x = vals[i*4]; o.y = vals[i*4+1]; o.z = vals[i*4+2]; o.w = vals[i*4+3];
                    d1[i] = o;
                }
                *(uint4*)((unsigned short*)C2 + off) = pack8(vals);
            } else {  // EPI == 2
                #pragma unroll
                for (int i = 0; i < 2; i++) {
                    float4 ga = *(const float4*)(e0 + mc0 + i * 4);
                    float4 be = *(const float4*)(e1 + mc0 + i * 4);
                    float4 mm = *(const float4*)(e2 + mc0 + i * 4);
                    float4 vv = *(const float4*)(e3 + mc0 + i * 4);
                    vals[i*4+0] = gelu_fast(ga.x * (vals[i*4+0] - mm.x) * rsqrtf(vv.x + EPSV) + be.x);
                    vals[i*4+1] = gelu_fast(ga.y * (vals[i*4+1] - mm.y) * rsqrtf(vv.y + EPSV) + be.y);
                    vals[i*4+2] = gelu_fast(ga.z * (vals[i*4+2] - mm.z) * rsqrtf(vv.z + EPSV) + be.z);
                    vals[i*4+3] = gelu_fast(ga.w * (vals[i*4+3] - mm.w) * rsqrtf(vv.w + EPSV) + be.w);
                }
                *(uint4*)((unsigned short*)C1 + off) = pack8(vals);
            }
        }
    }
}

// ---------- exact-f32 window pooling of h (recomputed from x_pm) ----------
__global__ __launch_bounds__(256) void poolh_k(const float* __restrict__ x_pm,
    const float* __restrict__ g1, const float* __restrict__ b1,
    const float* __restrict__ m1, const float* __restrict__ v1,
    float* __restrict__ ph)
{
    __shared__ float part[4][256];
    __shared__ float gam[256], bet[256], mu[256], rst[256];
    const int n = blockIdx.x, b = blockIdx.y, t = threadIdx.x;
    gam[t] = g1[t]; bet[t] = b1[t]; mu[t] = m1[t]; rst[t] = rsqrtf(v1[t] + EPSV);
    __syncthreads();
    const int c4 = (t & 63) * 4, pg = t >> 6;
    float s0 = 0.f, s1 = 0.f, s2 = 0.f, s3 = 0.f;
    for (int j = pg; j < 49; j += 4) {
        int p = ((n >> 3) * 7 + j / 7) * 56 + (n & 7) * 7 + j % 7;
        float4 vx = *(const float4*)(x_pm + ((size_t)b * PP + p) * 256 + c4);
        s0 += gelu_f(gam[c4+0] * (vx.x - mu[c4+0]) * rst[c4+0] + bet[c4+0]);
        s1 += gelu_f(gam[c4+1] * (vx.y - mu[c4+1]) * rst[c4+1] + bet[c4+1]);
        s2 += gelu_f(gam[c4+2] * (vx.z - mu[c4+2]) * rst[c4+2] + bet[c4+2]);
        s3 += gelu_f(gam[c4+3] * (vx.w - mu[c4+3]) * rst[c4+3] + bet[c4+3]);
    }
    part[pg][c4 + 0] = s0; part[pg][c4 + 1] = s1; part[pg][c4 + 2] = s2; part[pg][c4 + 3] = s3;
    __syncthreads();
    float tot = part[0][t] + part[1][t] + part[2][t] + part[3][t];
    ph[((size_t)b * 64 + n) * 256 + t] = tot * (1.0f / 49.0f);
}

// ---------- qr/kr = poolh . Wq^T / Wk^T (f32 exact) ----------
__global__ __launch_bounds__(256) void qrkr_k(const float* __restrict__ ph,
    const float* __restrict__ Wqkv, float* __restrict__ qr, float* __restrict__ kr)
{
    __shared__ float row[256];
    const int n = blockIdx.x, b = blockIdx.y, t = threadIdx.x;
    row[t] = ph[((size_t)b * 64 + n) * 256 + t];
    __syncthreads();
    const float* wq = Wqkv + (size_t)t * 256;
    const float* wk = Wqkv + (size_t)(256 + t) * 256;
    float aq = 0.f, ak = 0.f;
    #pragma unroll 4
    for (int k = 0; k < 256; k += 4) {
        float4 a4 = *(const float4*)(wq + k);
        float4 b4 = *(const float4*)(wk + k);
        aq += row[k]*a4.x + row[k+1]*a4.y + row[k+2]*a4.z + row[k+3]*a4.w;
        ak += row[k]*b4.x + row[k+1]*b4.y + row[k+2]*b4.z + row[k+3]*b4.w;
    }
    qr[((size_t)b * 64 + n) * 256 + t] = aq;
    kr[((size_t)b * 64 + n) * 256 + t] = ak;
}

// ---------- aff row + top-8 (one wave per (b,n)) ----------
__global__ __launch_bounds__(64) void topk_k(const float* __restrict__ qr,
    const float* __restrict__ kr, int* __restrict__ idxb)
{
    const int n = blockIdx.x, b_ = blockIdx.y;
    const int tid = threadIdx.x;
    __shared__ float qrow[256];
    *reinterpret_cast<float4*>(&qrow[tid * 4]) =
        *reinterpret_cast<const float4*>(qr + ((size_t)(b_ * 64) + n) * 256 + tid * 4);
    __syncthreads();
    const float* kp = kr + ((size_t)(b_ * 64) + tid) * 256;
    float av = 0.f;
    #pragma unroll 4
    for (int c = 0; c < 256; c++) av = fmaf(qrow[c], kp[c], av);
    for (int t = 0; t < 8; t++) {
        float v = av; int id = tid;
        #pragma unroll
        for (int off = 32; off; off >>= 1) {
            float v2 = __shfl_xor(v, off);
            int id2 = __shfl_xor(id, off);
            if (v2 > v || (v2 == v && id2 < id)) { v = v2; id = id2; }
        }
        if (tid == 0) idxb[((b_ * 64) + n) * 8 + t] = id;
        if (tid == id) av = -1e30f;
    }
}

// ---------- MFMA flash attention: fixed-shift softmax, 16KB LDS (4 blocks/CU) ----------
// Ks [64][32] unit-XOR (GEMM-proven, validated r12); Vt [32][64] unit-XOR;
// Pr [4][16][64] unit-XOR. Total LDS = 16384 B exactly.
__global__ __launch_bounds__(256) void attn_mfma_k(const unsigned short* __restrict__ qkv,
    const int* __restrict__ idxb, unsigned short* __restrict__ msg)
{
    __shared__ __align__(16) unsigned short Ks[64 * 32];
    __shared__ __align__(16) unsigned short Vt[32 * 64];
    __shared__ __align__(16) unsigned short Pr[4][16 * 64];
    const int n = blockIdx.x, h = blockIdx.y, b = blockIdx.z;
    const int tid = threadIdx.x;
    const int w = tid >> 6, lane = tid & 63, g = lane >> 4, l15 = lane & 15;

    // Vt must be zeroed (P=0 x NaN-garbage would poison PV); Ks pad rows are
    // select-masked after exp so no init needed.
    for (int e = tid; e < 32 * 64; e += 256) Vt[e] = 0;

    const int iq = w * 16 + l15;
    bf16x8 qf = {0, 0, 0, 0, 0, 0, 0, 0};
    if (iq < 49) {
        int p = ((n >> 3) * 7 + iq / 7) * 56 + (n & 7) * 7 + iq % 7;
        qf = *(const bf16x8*)(qkv + ((size_t)b * PP + p) * 768 + h * 32 + g * 8);
    }
    int widx[8];
    {
        const int* ip = idxb + ((b * 64) + n) * 8;
        #pragma unroll
        for (int t = 0; t < 8; t++) widx[t] = ip[t];
    }
    const f32x4 vzero = {0.f, 0.f, 0.f, 0.f};
    f32x4 o0 = vzero, o1 = vzero;
    float lsum = 0.f;

    const bool act = tid < 196;
    const int jrow = tid >> 2, c8 = (tid & 3) * 8;
    uint4 kk_r = {0,0,0,0}, vv_r = {0,0,0,0};
    auto LOADW = [&](int t) {
        int wsrc = widx[t];
        int p = ((wsrc >> 3) * 7 + jrow / 7) * 56 + (wsrc & 7) * 7 + jrow % 7;
        const unsigned short* srcp = qkv + ((size_t)b * PP + p) * 768 + 256 + h * 32 + c8;
        kk_r = *(const uint4*)srcp;
        vv_r = *(const uint4*)(srcp + 256);
    };
    if (act) LOADW(0);

    for (int t = 0; t < 8; t++) {
        __syncthreads();
        if (act) {
            // Ks: row jrow, unit (c8>>3) ^ ((jrow>>1)&3)
            *(uint4*)&Ks[jrow * 32 + (((c8 >> 3) ^ ((jrow >> 1) & 3)) << 3)] = kk_r;
            const unsigned short* pv = (const unsigned short*)&vv_r;
            #pragma unroll
            for (int jj = 0; jj < 8; jj++) {
                // Vt: row dh=c8+jj (dh&7 == jj), elem j=jrow -> unit (jrow>>3)^jj, inner jrow&7
                Vt[(c8 + jj) * 64 + (((jrow >> 3) ^ jj) << 3) + (jrow & 7)] = pv[jj];
            }
            if (t < 7) LOADW(t + 1);
        }
        __syncthreads();
        // S^T = mfma(K, Q): lane l15 = q-row i; reg (nf,r) = key j = nf*16+g*4+r
        f32x4 s[4];
        #pragma unroll
        for (int nf = 0; nf < 4; nf++) {
            const int row = nf * 16 + l15;
            bf16x8 kf = *(const bf16x8*)&Ks[row * 32 + ((g ^ ((row >> 1) & 3)) << 3)];
            s[nf] = __builtin_amdgcn_mfma_f32_16x16x32_bf16(kf, qf, vzero, 0, 0, 0);
        }
        float pe[16];
        #pragma unroll
        for (int nf = 0; nf < 4; nf++)
            #pragma unroll
            for (int r = 0; r < 4; r++) {
                int j = nf * 16 + g * 4 + r;
                float e_ = __expf(s[nf][r] - 10.0f);
                float pv_ = (j < 49) ? e_ : 0.f;
                pe[nf * 4 + r] = pv_;
                lsum += pv_;
            }
        #pragma unroll
        for (int nf = 0; nf < 4; nf++) {
            uint2 pw;
            pw.x = (unsigned)f2bf(pe[nf*4+0]) | ((unsigned)f2bf(pe[nf*4+1]) << 16);
            pw.y = (unsigned)f2bf(pe[nf*4+2]) | ((unsigned)f2bf(pe[nf*4+3]) << 16);
            // Pr: row l15, 16B-unit (2nf+(g>>1)) ^ (l15&7), inner 8B half (g&1)
            *(uint2*)&Pr[w][l15 * 64 + ((((nf << 1) + (g >> 1)) ^ (l15 & 7)) << 3) + ((g & 1) << 2)] = pw;
        }
        asm volatile("s_waitcnt lgkmcnt(0)" ::: "memory");
        __builtin_amdgcn_sched_barrier(0);
        #pragma unroll
        for (int ks = 0; ks < 2; ks++) {
            // pf: conceptual cols j0..j0+7 (j0 = ks*32+g*8) -> unit (4ks+g)^(l15&7)
            bf16x8 pf  = *(const bf16x8*)&Pr[w][l15 * 64 + ((((ks << 2) + g) ^ (l15 & 7)) << 3)];
            bf16x8 vf0 = *(const bf16x8*)&Vt[l15 * 64 + ((((ks << 2) + g) ^ (l15 & 7)) << 3)];
            bf16x8 vf1 = *(const bf16x8*)&Vt[(16 + l15) * 64 + ((((ks << 2) + g) ^ (l15 & 7)) << 3)];
            o0 = __builtin_amdgcn_mfma_f32_16x16x32_bf16(vf0, pf, o0, 0, 0, 0);
            o1 = __builtin_amdgcn_mfma_f32_16x16x32_bf16(vf1, pf, o1, 0, 0, 0);
        }
    }
    lsum += __shfl_xor(lsum, 16);
    lsum += __shfl_xor(lsum, 32);
    if (iq < 49) {
        float inv = 1.0f / lsum;
        int p = ((n >> 3) * 7 + iq / 7) * 56 + (n & 7) * 7 + iq % 7;
        size_t off = ((size_t)b * PP + p) * 256 + h * 32;
        uint2 w0, w1;
        w0.x = (unsigned)f2bf(o0[0]*inv) | ((unsigned)f2bf(o0[1]*inv) << 16);
        w0.y = (unsigned)f2bf(o0[2]*inv) | ((unsigned)f2bf(o0[3]*inv) << 16);
        w1.x = (unsigned)f2bf(o1[0]*inv) | ((unsigned)f2bf(o1[1]*inv) << 16);
        w1.y = (unsigned)f2bf(o1[2]*inv) | ((unsigned)f2bf(o1[3]*inv) << 16);
        *(uint2*)(msg + off + g * 4) = w0;
        *(uint2*)(msg + off + 16 + g * 4) = w1;
    }
}

// ---------- depthwise 3x3 + bn3 + gelu, position-major ----------
__global__ __launch_bounds__(256) void dwconv_k(const unsigned short* __restrict__ in,
    const float* __restrict__ w9,
    const float* __restrict__ g3, const float* __restrict__ b3,
    const float* __restrict__ m3, const float* __restrict__ v3,
    unsigned short* __restrict__ out)
{
    __shared__ __align__(16) unsigned short tl[100 * 64];
    const int sx = blockIdx.x % 7, sy = blockIdx.x / 7;
    const int c0 = blockIdx.y * 64, b = blockIdx.z;
    const int t = threadIdx.x;
    for (int e = t; e < 800; e += 256) {
        int pos = e >> 3, c8 = (e & 7) * 8;
        int iy = sy * 8 + pos / 10 - 1, ix = sx * 8 + pos % 10 - 1;
        uint4 val = {0u, 0u, 0u, 0u};
        if (iy >= 0 && iy < 56 && ix >= 0 && ix < 56)
            val = *(const uint4*)(in + ((size_t)b * PP + iy * 56 + ix) * 1024 + c0 + c8);
        *(uint4*)&tl[pos * 64 + c8] = val;
    }
    __syncthreads();
    const int c2 = (t & 31) * 2, pg = t >> 5;
    const int c = c0 + c2;
    float w0[9], w1[9];
    #pragma unroll
    for (int i = 0; i < 9; i++) { w0[i] = w9[c * 9 + i]; w1[i] = w9[(c + 1) * 9 + i]; }
    const float ga0 = g3[c], be0 = b3[c], mu0 = m3[c], rs0 = rsqrtf(v3[c] + EPSV);
    const float ga1 = g3[c+1], be1 = b3[c+1], mu1 = m3[c+1], rs1 = rsqrtf(v3[c+1] + EPSV);
    #pragma unroll
    for (int q = 0; q < 8; q++) {
        int pos = pg * 8 + q, y = pos >> 3, xq = pos & 7;
        float s0 = 0.f, s1 = 0.f;
        #pragma unroll
        for (int dy = 0; dy < 3; dy++)
            #pragma unroll
            for (int dx = 0; dx < 3; dx++) {
                unsigned int u = *(const unsigned int*)&tl[((y + dy) * 10 + xq + dx) * 64 + c2];
                s0 = fmaf(bf2f((unsigned short)(u & 0xffffu)), w0[dy * 3 + dx], s0);
                s1 = fmaf(bf2f((unsigned short)(u >> 16)), w1[dy * 3 + dx], s1);
            }
        float y0 = gelu_fast(ga0 * (s0 - mu0) * rs0 + be0);
        float y1 = gelu_fast(ga1 * (s1 - mu1) * rs1 + be1);
        unsigned int ow = (unsigned int)f2bf(y0) | ((unsigned int)f2bf(y1) << 16);
        size_t off = ((size_t)b * PP + (sy * 8 + y) * 56 + sx * 8 + xq) * 1024 + c;
        *(unsigned int*)&out[off] = ow;
    }
}

// ---------- launch ----------
extern "C" void kernel_launch(void* const* d_in, const int* in_sizes, int n_in,
                              void* d_out, int out_size, void* d_ws, size_t ws_size,
                              hipStream_t stream)
{
    const float* x      = (const float*)d_in[0];
    const float* g1     = (const float*)d_in[1];
    const float* b1     = (const float*)d_in[2];
    const float* m1     = (const float*)d_in[3];
    const float* v1     = (const float*)d_in[4];
    const float* Wqkv   = (const float*)d_in[5];
    const float* Wmerge = (const float*)d_in[6];
    const float* bmerge = (const float*)d_in[7];
    const float* W1     = (const float*)d_in[8];
    const float* g2     = (const float*)d_in[9];
    const float* b2     = (const float*)d_in[10];
    const float* m2     = (const float*)d_in[11];
    const float* v2     = (const float*)d_in[12];
    const float* Wdw    = (const float*)d_in[13];
    const float* g3     = (const float*)d_in[14];
    const float* b3     = (const float*)d_in[15];
    const float* m3     = (const float*)d_in[16];
    const float* v3     = (const float*)d_in[17];
    const float* W2     = (const float*)d_in[18];
    const float* g4     = (const float*)d_in[19];
    const float* b4     = (const float*)d_in[20];
    const float* m4     = (const float*)d_in[21];
    const float* v4     = (const float*)d_in[22];

    char* ws = (char*)d_ws;
    float*          x_pm   = (float*)(ws + 0);                  // 25,690,112
    float*          x2_pm  = (float*)(ws + 25690112);           // 25,690,112
    unsigned short* x2_bf  = (unsigned short*)(ws + 51380224);  // 12,845,056
    unsigned short* qkv_pm = (unsigned short*)(ws + 64225280);  // 38,535,168
    unsigned short* msg_pm = (unsigned short*)(ws + 102760448); // 12,845,056
    unsigned short* t1     = (unsigned short*)(ws + 115605504); // 51,380,224 (h_bf aliases)
    unsigned short* h_bf   = t1;
    unsigned short* t2     = (unsigned short*)(ws + 166985728); // 51,380,224
    float*          ph     = (float*)(ws + 218365952);          // 524,288
    float*          qr     = (float*)(ws + 218890240);          // 524,288
    float*          kr     = (float*)(ws + 219414528);          // 524,288
    int*            idxb   = (int*)(ws + 219938816);            // 16,384
    unsigned short* Wqkv_b = (unsigned short*)(ws + 219955200); // 393,216
    unsigned short* Wmrg_b = (unsigned short*)(ws + 220348416); // 131,072
    unsigned short* W1_b   = (unsigned short*)(ws + 220479488); // 524,288
    unsigned short* W2_b   = (unsigned short*)(ws + 221003776); // 524,288
    if (ws_size < 221528064) return;

    cvt_all_k<<<3072, 256, 0, stream>>>(Wqkv, Wmerge, W1, W2, Wqkv_b, Wmrg_b, W1_b, W2_b);
    transin_k<<<dim3(49, 4, BB), 256, 0, stream>>>(x, g1, b1, m1, v1, x_pm, h_bf);
    // qkv = h . Wqkv^T (q pre-scaled)
    gemm_mfma_k<0><<<dim3(196, 6), 512, 0, stream>>>(h_bf, Wqkv_b, 256, 768,
        qkv_pm, nullptr, nullptr, nullptr, nullptr, nullptr, nullptr);
    poolh_k<<<dim3(64, BB), 256, 0, stream>>>(x_pm, g1, b1, m1, v1, ph);
    qrkr_k<<<dim3(64, BB), 256, 0, stream>>>(ph, Wqkv, qr, kr);
    topk_k<<<dim3(64, BB), 64, 0, stream>>>(qr, kr, idxb);
    attn_mfma_k<<<dim3(64, 8, BB), 256, 0, stream>>>(qkv_pm, idxb, msg_pm);
    // x2 = x + msg . Wmerge^T + b_merge
    gemm_mfma_k<1><<<dim3(196, 2), 512, 0, stream>>>(msg_pm, Wmrg_b, 256, 256,
        x2_pm, x2_bf, bmerge, nullptr, nullptr, nullptr, x_pm);
    // t1 = gelu(bn2(x2 . W1^T))
    gemm_mfma_k<2><<<dim3(196, 8), 512, 0, stream>>>(x2_bf, W1_b, 256, 1024,
        t1, nullptr, g2, b2, m2, v2, nullptr);
    dwconv_k<<<dim3(49, 16, BB), 256, 0, stream>>>(t1, Wdw, g3, b3, m3, v3, t2);
    // d_out (NCHW) = x2 + bn4(t2 . W2^T)  — transout fused into epilogue
    gemm_mfma_k<3><<<dim3(196, 2), 512, 0, stream>>>(t2, W2_b, 1024, 256,
        (float*)d_out, nullptr, g4, b4, m4, v4, x2_pm);
}